// Round 6
// baseline (8194.244 us; speedup 1.0000x reference)
//
#include <hip/hip_runtime.h>

#define EPI_BF16D 0
#define EPI_SUMF32 1
#define EPI_LSTM1 2
#define EPI_LSTM2 3
#define EPI_LOGITS 4

#define T_ 40
#define VOC_ 10000

typedef __attribute__((ext_vector_type(8))) short bf16x8;
typedef __attribute__((ext_vector_type(4))) short short4v;
typedef __attribute__((ext_vector_type(8))) short short8v;
typedef __attribute__((ext_vector_type(4))) float float4v;
typedef __attribute__((ext_vector_type(4))) float f32x4;

__device__ __forceinline__ float bf2f(short s) {
  unsigned u = ((unsigned)(unsigned short)s) << 16;
  float f; __builtin_memcpy(&f, &u, 4); return f;
}
__device__ __forceinline__ short f2bf(float f) {
  unsigned u; __builtin_memcpy(&u, &f, 4);
  u += 0x7FFFu + ((u >> 16) & 1u);
  return (short)(u >> 16);
}
__device__ __forceinline__ float sigm(float x) { return 1.f / (1.f + expf(-x)); }

// packed W layout: W[row][k] at (row>>4)*16*K + (k>>3)*128 + (row&15)*8 + (k&7)
__device__ __forceinline__ size_t pkidx(int row, int k, int K) {
  return (size_t)(row >> 4) * 16 * K + (size_t)(k >> 3) * 128 + (size_t)((row & 15) * 8 + (k & 7));
}

// ---------------- packing kernels ----------------

__global__ __launch_bounds__(256) void k_f2bf_split(const float* __restrict__ s,
    short* __restrict__ dh, short* __restrict__ dl, long n4) {
  long i = (long)blockIdx.x * 256 + threadIdx.x;
  long stride = (long)gridDim.x * 256;
  for (; i < n4; i += stride) {
    float4v f = ((const float4v*)s)[i];
    short4v oh, ol;
    #pragma unroll
    for (int j = 0; j < 4; j++) {
      short h = f2bf(f[j]); oh[j] = h; ol[j] = f2bf(f[j] - bf2f(h));
    }
    ((short4v*)dh)[i] = oh;
    ((short4v*)dl)[i] = ol;
  }
}

__global__ __launch_bounds__(256) void k_permpk(short* __restrict__ dh, short* __restrict__ dl,
    const float* __restrict__ s1, int ld1, int col0, int K1,
    const float* __restrict__ s2, int ld2, int Ktot) {
  int K4 = Ktot >> 2;
  long n4 = 4096L * K4;
  long stride = (long)gridDim.x * 256;
  for (long i = (long)blockIdx.x * 256 + threadIdx.x; i < n4; i += stride) {
    int p = (int)(i / K4);
    int c = ((int)(i % K4)) << 2;
    int orig = ((p & 3) << 10) + (p >> 2);
    const float* src = (c < K1) ? (s1 + (long)orig * ld1 + col0 + c)
                                : (s2 + (long)orig * ld2 + (c - K1));
    float4v f = *(const float4v*)src;
    short4v oh, ol;
    #pragma unroll
    for (int j = 0; j < 4; j++) {
      short h = f2bf(f[j]); oh[j] = h; ol[j] = f2bf(f[j] - bf2f(h));
    }
    size_t d = pkidx(p, c, Ktot);
    *(short4v*)&dh[d] = oh;
    if (dl) *(short4v*)&dl[d] = ol;
  }
}

__global__ __launch_bounds__(256) void k_packpk(short* __restrict__ dh, short* __restrict__ dl,
    const float* __restrict__ src, int ld, int Nr, int Nsrc, int K) {
  int K4 = K >> 2;
  long n4 = (long)Nr * K4;
  long stride = (long)gridDim.x * 256;
  for (long i = (long)blockIdx.x * 256 + threadIdx.x; i < n4; i += stride) {
    int row = (int)(i / K4);
    int c = ((int)(i % K4)) << 2;
    float4v f = {0.f, 0.f, 0.f, 0.f};
    if (row < Nsrc) f = *(const float4v*)(src + (long)row * ld + c);
    short4v oh, ol;
    #pragma unroll
    for (int j = 0; j < 4; j++) {
      short h = f2bf(f[j]); oh[j] = h; ol[j] = f2bf(f[j] - bf2f(h));
    }
    size_t d = pkidx(row, c, K);
    *(short4v*)&dh[d] = oh;
    if (dl) *(short4v*)&dl[d] = ol;
  }
}

__global__ __launch_bounds__(256) void k_perm_bias(float* __restrict__ d1, const float* __restrict__ s1,
                                                   float* __restrict__ d2, const float* __restrict__ s2) {
  int p = blockIdx.x * 256 + threadIdx.x;
  if (p < 4096) {
    int orig = ((p & 3) << 10) + (p >> 2);
    d1[p] = s1[orig];
    d2[p] = s2[orig];
  }
}

__global__ __launch_bounds__(256) void k_gather_emb(short* __restrict__ dst, const float* __restrict__ embW,
                                                    const int* __restrict__ cap) {
  int i = blockIdx.x * 256 + threadIdx.x;  // 5120*128
  if (i >= 5120 * 128) return;
  int row = i >> 7, c8 = (i & 127) << 3;
  int tok = cap[row];
  const float4v* s = (const float4v*)(embW + (long)tok * 1024 + c8);
  float4v f0 = s[0], f1 = s[1];
  short8v o;
  #pragma unroll
  for (int j = 0; j < 4; j++) { o[j] = f2bf(f0[j]); o[4 + j] = f2bf(f1[j]); }
  *(short8v*)(dst + (long)row * 1024 + c8) = o;
}

// ---------------- slab GEMM with fused last-block split-K reduction + epilogue ----------------
// C[M=128/tile, N] = A @ Wpk^T. NT=64. Grid (Ntiles, KS, Mtiles); Kchunk = NC*128.
// GEMM: W frags preloaded to reg ring, A staged per-128k slab in XOR-swizzled LDS.
// Each block writes its f32 partial tile; LAST block per (x,z) tile (device counter,
// release/acquire threadfence) sums partials in fixed order and runs the epilogue.

template<int NC, int KS, bool SA, bool SW, int EPI>
__global__ __launch_bounds__(256) void k_g4(
    const short* __restrict__ A, const short* __restrict__ Alo, int lda,
    const short* __restrict__ W, const short* __restrict__ Wlo, int K,
    int Npad, int Mtot,
    float* __restrict__ part, short* __restrict__ outbf,
    int* __restrict__ cnt, int cbase,
    const float* __restrict__ bias, float* __restrict__ outf, int outN,
    const float* __restrict__ zuv, const short* __restrict__ zemb,
    float* __restrict__ cstate,
    const short* __restrict__ xcur_hi, const short* __restrict__ xcur_lo,
    short* __restrict__ xnext_hi, short* __restrict__ xnext_lo,
    short* __restrict__ x2_hi, short* __restrict__ x2_lo,
    short* __restrict__ h2n_hi, short* __restrict__ h2n_lo,
    const int* __restrict__ lengths, int t,
    float* __restrict__ out_logits) {
  __shared__ short sh[SA ? 32768 : 16384];
  const int tid = threadIdx.x;
  const int l = tid & 63, w = tid >> 6;
  const int rif = l & 15, kg = l >> 4;
  const int n0 = blockIdx.x * 64;
  const int k0 = blockIdx.y * NC * 128;
  const int mbase = blockIdx.z * 128;

  f32x4 acc[8];
  #pragma unroll
  for (int m = 0; m < 8; m++) acc[m] = (f32x4){0.f, 0.f, 0.f, 0.f};

  bf16x8 wh[2][4], wl[2][4];
  const size_t wtile = (size_t)(n0 / 16 + w) * 16 * K + (size_t)l * 8;

  auto loadW = [&](int c, int slot) {
    size_t base = wtile + (size_t)((k0 + c * 128) >> 3) * 128;
    #pragma unroll
    for (int sk = 0; sk < 4; sk++) {
      wh[slot][sk] = *(const bf16x8*)(W + base + sk * 512);
      if (SW) wl[slot][sk] = *(const bf16x8*)(Wlo + base + sk * 512);
    }
  };
  auto stageA = [&](int c) {
    #pragma unroll
    for (int p = 0; p < (SA ? 2 : 1); p++) {
      const short* src = p ? Alo : A;
      #pragma unroll
      for (int j = 0; j < 8; j++) {
        int row = (j * 4 + w) * 4 + (l >> 4);
        int col = (l & 15) * 8;
        short8v v = *(const short8v*)(src + (size_t)(mbase + row) * lda + k0 + c * 128 + col);
        *(short8v*)&sh[p * 16384 + row * 128 + (col ^ ((row & 7) << 3))] = v;
      }
    }
  };
  auto compute = [&](int slot) {
    #pragma unroll
    for (int sk = 0; sk < 4; sk++) {
      int colb = ((sk * 32 + kg * 8) ^ ((rif & 7) << 3));
      #pragma unroll
      for (int m = 0; m < 8; m++) {
        int idx = (m * 16 + rif) * 128 + colb;
        bf16x8 ah = *(const bf16x8*)&sh[idx];
        acc[m] = __builtin_amdgcn_mfma_f32_16x16x32_bf16(ah, wh[slot][sk], acc[m], 0, 0, 0);
        if (SA) {
          bf16x8 al = *(const bf16x8*)&sh[16384 + idx];
          acc[m] = __builtin_amdgcn_mfma_f32_16x16x32_bf16(al, wh[slot][sk], acc[m], 0, 0, 0);
        }
        if (SW) acc[m] = __builtin_amdgcn_mfma_f32_16x16x32_bf16(ah, wl[slot][sk], acc[m], 0, 0, 0);
      }
    }
  };

  loadW(0, 0);
  stageA(0);
  __syncthreads();
  #pragma unroll
  for (int c = 0; c < NC; c++) {
    if (c + 1 < NC) loadW(c + 1, (c + 1) & 1);
    compute(c & 1);
    if (c + 1 < NC) {
      __syncthreads();
      stageA(c + 1);
      __syncthreads();
    }
  }

  const int colw = n0 + w * 16 + rif;
  if constexpr (EPI == EPI_BF16D) {
    #pragma unroll
    for (int m = 0; m < 8; m++)
      #pragma unroll
      for (int j = 0; j < 4; j++)
        outbf[(size_t)(mbase + m * 16 + kg * 4 + j) * Npad + colw] = f2bf(acc[m][j]);
    return;
  }

  // write partial tile
  #pragma unroll
  for (int m = 0; m < 8; m++)
    #pragma unroll
    for (int j = 0; j < 4; j++)
      part[((size_t)blockIdx.y * Mtot + mbase + m * 16 + kg * 4 + j) * Npad + colw] = acc[m][j];

  // last-block election: barrier drains each wave's stores to L2, release fence
  // writes back L2, device-scope atomic elects, acquire fence invalidates.
  __shared__ int lastFlag;
  __syncthreads();
  if (tid == 0) {
    __threadfence();
    int old = atomicAdd(&cnt[cbase + blockIdx.x + gridDim.x * blockIdx.z], 1);
    lastFlag = (old == KS - 1);
  }
  __syncthreads();
  if (!lastFlag) return;
  __threadfence();

  if constexpr (EPI == EPI_SUMF32) {
    for (int e = tid * 4; e < 8192; e += 1024) {
      int row = e >> 6, c = e & 63;
      int col = n0 + c;
      float4v a = *(const float4v*)&bias[col];
      #pragma unroll
      for (int s = 0; s < KS; s++) {
        float4v p = *(const float4v*)&part[((size_t)s * Mtot + mbase + row) * Npad + col];
        #pragma unroll
        for (int j = 0; j < 4; j++) a[j] += p[j];
      }
      *(float4v*)&outf[(size_t)(mbase + row) * outN + col] = a;
    }
  } else if constexpr (EPI == EPI_LOGITS) {
    for (int e = tid * 4; e < 8192; e += 1024) {
      int b = e >> 6, c = e & 63;
      int col = n0 + c;
      if (col < VOC_) {
        bool act = lengths[b] > t;
        float4v a = {0.f, 0.f, 0.f, 0.f};
        if (act) {
          a = *(const float4v*)&bias[col];
          #pragma unroll
          for (int s = 0; s < KS; s++) {
            float4v p = *(const float4v*)&part[((size_t)s * 128 + b) * Npad + col];
            #pragma unroll
            for (int j = 0; j < 4; j++) a[j] += p[j];
          }
        }
        *(float4v*)&out_logits[((size_t)b * T_ + t) * VOC_ + col] = a;
      }
    }
  } else {
    // LSTM epilogue: tile covers h in [n0/4, n0/4+16)
    #pragma unroll
    for (int i = 0; i < 8; i++) {
      int pid = i * 256 + tid;           // 2048 = 128 b x 16 hl
      int b = pid >> 4, hl = pid & 15;
      float4v g = {0.f, 0.f, 0.f, 0.f};
      #pragma unroll
      for (int s = 0; s < KS; s++) {
        float4v p = *(const float4v*)&part[((size_t)s * 128 + b) * Npad + n0 + hl * 4];
        #pragma unroll
        for (int j = 0; j < 4; j++) g[j] += p[j];
      }
      if constexpr (EPI == EPI_LSTM1) {
        float4v z = *(const float4v*)&zuv[(size_t)b * 4096 + n0 + hl * 4];   // includes b1
        short4v e4 = *(const short4v*)&zemb[((size_t)b * T_ + t) * 4096 + n0 + hl * 4];
        #pragma unroll
        for (int j = 0; j < 4; j++) g[j] += z[j] + bf2f(e4[j]);
      } else {
        float4v z = *(const float4v*)&bias[n0 + hl * 4];
        #pragma unroll
        for (int j = 0; j < 4; j++) g[j] += z[j];
      }
      int h = (n0 >> 2) + hl;
      float co = cstate[b * 1024 + h];
      float cn = sigm(g[1]) * co + sigm(g[0]) * tanhf(g[2]);
      float hn = sigm(g[3]) * tanhf(cn);
      bool act = lengths[b] > t;
      cstate[b * 1024 + h] = act ? cn : co;
      short hi16 = f2bf(hn);
      short lo16 = f2bf(hn - bf2f(hi16));
      if constexpr (EPI == EPI_LSTM1) {
        x2_hi[b * 4096 + 2048 + h] = hi16;
        x2_lo[b * 4096 + 2048 + h] = lo16;
        short oh = xcur_hi[b * 2048 + 1024 + h];
        short ol = xcur_lo[b * 2048 + 1024 + h];
        xnext_hi[b * 2048 + 1024 + h] = act ? hi16 : oh;
        xnext_lo[b * 2048 + 1024 + h] = act ? lo16 : ol;
        x2_hi[b * 4096 + 3072 + h] = xcur_hi[b * 2048 + h];
        x2_lo[b * 4096 + 3072 + h] = xcur_lo[b * 2048 + h];
      } else {
        h2n_hi[b * 1024 + h] = hi16;
        h2n_lo[b * 1024 + h] = lo16;
        short oh = xcur_hi[b * 2048 + h];
        short ol = xcur_lo[b * 2048 + h];
        xnext_hi[b * 2048 + h] = act ? hi16 : oh;
        xnext_lo[b * 2048 + h] = act ? lo16 : ol;
      }
    }
  }
  if (tid == 0) cnt[cbase + blockIdx.x + gridDim.x * blockIdx.z] = 0;  // self-reset
}

// ---------------- fused attention tail, one block per batch ----------------
__global__ __launch_bounds__(256) void k_attn(
    short* __restrict__ x2_hi, short* __restrict__ x2_lo,
    const float* __restrict__ haB, const float* __restrict__ wa,
    const float* __restrict__ ba, const float* __restrict__ Va,
    const float* __restrict__ Vmat) {
  const int b = blockIdx.x, tid = threadIdx.x;
  __shared__ float ha_sh[256];
  __shared__ float wa_sh[256];
  __shared__ float logit_sh[40];
  __shared__ float p_sh[40];
  ha_sh[tid] = haB[b * 256 + tid];       // includes bha
  wa_sh[tid] = wa[tid];
  __syncthreads();
  {
    const int r0 = tid >> 3, sl = tid & 7;
    const float ba0 = ba[0];
    for (int r = r0; r < 36; r += 32) {
      const float4v* va4 = (const float4v*)(Va + ((long)b * 36 + r) * 256 + sl * 32);
      float part = 0.f;
      #pragma unroll
      for (int q = 0; q < 8; q++) {
        float4v v4 = va4[q];
        #pragma unroll
        for (int j = 0; j < 4; j++) {
          int ph = sl * 32 + q * 4 + j;
          part += tanhf(v4[j] + ha_sh[ph]) * wa_sh[ph];
        }
      }
      part += __shfl_down(part, 4, 8);
      part += __shfl_down(part, 2, 8);
      part += __shfl_down(part, 1, 8);
      if (sl == 0) logit_sh[r] = part + ba0;
    }
  }
  __syncthreads();
  if (tid < 64) {
    float v = (tid < 36) ? logit_sh[tid] : -3.4e38f;
    float m = v;
    #pragma unroll
    for (int off = 32; off > 0; off >>= 1) m = fmaxf(m, __shfl_xor(m, off));
    float e = (tid < 36) ? expf(v - m) : 0.f;
    float s = e;
    #pragma unroll
    for (int off = 32; off > 0; off >>= 1) s += __shfl_xor(s, off);
    if (tid < 36) p_sh[tid] = e / s;
  }
  __syncthreads();
  {
    float av[8];
    #pragma unroll
    for (int j = 0; j < 8; j++) av[j] = 0.f;
    const float* vb = Vmat + (long)b * (36 * 2048) + tid * 8;
    for (int r = 0; r < 36; r++) {
      float p = p_sh[r];
      float4v v0 = *(const float4v*)(vb + (long)r * 2048);
      float4v v1 = *(const float4v*)(vb + (long)r * 2048 + 4);
      #pragma unroll
      for (int j = 0; j < 4; j++) { av[j] += p * v0[j]; av[4 + j] += p * v1[j]; }
    }
    short8v oh, ol;
    #pragma unroll
    for (int j = 0; j < 8; j++) {
      short h = f2bf(av[j]);
      oh[j] = h;
      ol[j] = f2bf(av[j] - bf2f(h));
    }
    *(short8v*)(x2_hi + b * 4096 + tid * 8) = oh;
    *(short8v*)(x2_lo + b * 4096 + tid * 8) = ol;
  }
}

// 11 state-pointer slots (zuv, zemb, cstate, xcur_hi, xcur_lo, xnext_hi, xnext_lo,
// x2_hi, x2_lo, h2n_hi, h2n_lo)
#define NULSTATE nullptr, nullptr, nullptr, nullptr, nullptr, nullptr, nullptr, nullptr, nullptr, nullptr, nullptr

// ---------------- host launcher ----------------
extern "C" void kernel_launch(void* const* d_in, const int* in_sizes, int n_in,
                              void* d_out, int out_size, void* d_ws, size_t ws_size,
                              hipStream_t stream) {
  const float* Vmat = (const float*)d_in[0];
  const float* uv   = (const float*)d_in[2];
  const int* captions = (const int*)d_in[3];
  const int* lengths  = (const int*)d_in[4];
  const float* embW = (const float*)d_in[5];
  const float* Wi1 = (const float*)d_in[6];
  const float* Wh1 = (const float*)d_in[7];
  const float* b1  = (const float*)d_in[8];
  const float* Wi2 = (const float*)d_in[9];
  const float* Wh2 = (const float*)d_in[10];
  const float* b2  = (const float*)d_in[11];
  const float* Wva = (const float*)d_in[12];
  const float* bva = (const float*)d_in[13];
  const float* Wha = (const float*)d_in[14];
  const float* bha = (const float*)d_in[15];
  const float* wa  = (const float*)d_in[16];
  const float* ba  = (const float*)d_in[17];
  const float* Wl  = (const float*)d_in[18];
  const float* bl  = (const float*)d_in[19];
  (void)in_sizes; (void)n_in; (void)out_size; (void)ws_size;

  char* ws = (char*)d_ws;
  size_t off = 0;
  auto alloc = [&](size_t bytes) { void* p = ws + off; off += (bytes + 255) & ~255UL; return p; };
  short* W1dHi = (short*)alloc(4096L * 2048 * 2);
  short* W1dLo = (short*)alloc(4096L * 2048 * 2);
  short* W2dHi = (short*)alloc(4096L * 4096 * 2);   // staging arena pre-loop
  short* W2dLo = (short*)alloc(4096L * 4096 * 2);
  short* WlPK  = (short*)alloc(10048L * 1024 * 2);
  short* WhaHi = (short*)alloc(256L * 1024 * 2);
  short* WhaLo = (short*)alloc(256L * 1024 * 2);
  float* VaBuf = (float*)alloc(4608L * 256 * 4);
  float* Z1uvB = (float*)alloc(128L * 4096 * 4);
  short* Z1embB = (short*)alloc(5120L * 4096 * 2);  // hosts Vmat hi/lo split pre-loop
  float* partG = (float*)alloc(8L * 128 * 10048 * 4); // 20.6MB partials arena; W1e+Aemb pre-loop
  float* haPart = (float*)alloc(8L * 128 * 256 * 4);
  float* haB  = (float*)alloc(128L * 256 * 4);
  int*   cnt  = (int*)alloc(4096 * 4);
  float* b1P = (float*)alloc(4096 * 4);
  float* b2P = (float*)alloc(4096 * 4);
  short* x1Hi = (short*)alloc(2L * 128 * 2048 * 2);
  short* x1Lo = (short*)alloc(2L * 128 * 2048 * 2);
  short* x2Hi = (short*)alloc(128L * 4096 * 2);     // [av | h1n | h2]
  short* x2Lo = (short*)alloc(128L * 4096 * 2);
  short* h2nHi = (short*)alloc(128L * 1024 * 2);
  short* h2nLo = (short*)alloc(128L * 1024 * 2);
  float* c1 = (float*)alloc(128L * 1024 * 4);
  float* c2 = (float*)alloc(128L * 1024 * 4);

  // aliased one-time regions
  short* W1uvHi = W2dHi;
  short* W1uvLo = W2dHi + 4096L * 2048;
  float* zuvPart = (float*)(W2dHi + 4096L * 4096);             // [8][128][4096] f32
  short* uvHi = W2dHi + 4096L * 4096 + 4096L * 2048 + 2097152;
  short* uvLo = uvHi + 128L * 2048;
  short* WvaHi = uvLo + 128L * 2048;
  short* WvaLo = WvaHi + 256L * 2048;
  float* vaPart = (float*)W2dHi;                               // [8][4608][256] after W1uv dead
  short* W1ePk = (short*)partG;
  short* AembBF = (short*)partG + 4096L * 1024;
  short* VmatHi = Z1embB;
  short* VmatLo = Z1embB + 4608L * 2048;

  (void)hipMemsetAsync(cnt, 0, 4096 * 4, stream);
  (void)hipMemsetAsync(x1Hi, 0, 2L * 128 * 2048 * 2, stream);
  (void)hipMemsetAsync(x1Lo, 0, 2L * 128 * 2048 * 2, stream);
  (void)hipMemsetAsync(c1, 0, 128L * 1024 * 4, stream);
  (void)hipMemsetAsync(c2, 0, 128L * 1024 * 4, stream);

  // ---- packing ----
  k_packpk<<<2048, 256, 0, stream>>>(WlPK, nullptr, Wl, 1024, 10048, 10000, 1024);
  k_packpk<<<256, 256, 0, stream>>>(WhaHi, WhaLo, Wha, 1024, 256, 256, 1024);
  k_packpk<<<512, 256, 0, stream>>>(WvaHi, WvaLo, Wva, 2048, 256, 256, 2048);
  k_permpk<<<2048, 256, 0, stream>>>(W1dHi, W1dLo, Wi1, 4096, 0, 1024, Wh1, 1024, 2048);
  k_permpk<<<2048, 256, 0, stream>>>(W1uvHi, W1uvLo, Wi1, 4096, 1024, 2048, Wi1, 4096, 2048);
  k_permpk<<<1024, 256, 0, stream>>>(W1ePk, nullptr, Wi1, 4096, 3072, 1024, Wi1, 4096, 1024);
  k_perm_bias<<<16, 256, 0, stream>>>(b1P, b1, b2P, b2);
  k_gather_emb<<<2560, 256, 0, stream>>>(AembBF, embW, captions);
  k_f2bf_split<<<2048, 256, 0, stream>>>(Vmat, VmatHi, VmatLo, 128L * 36 * 2048 / 4);
  k_f2bf_split<<<64, 256, 0, stream>>>(uv, uvHi, uvLo, 128L * 2048 / 4);

  // Z1uv = uv @ W1uv^T + b1 (perm) -> f32 (fused sum, cnt base 640)
  k_g4<2, 8, true, true, EPI_SUMF32><<<dim3(64, 8, 1), 256, 0, stream>>>(
      uvHi, uvLo, 2048, W1uvHi, W1uvLo, 2048, 4096, 128,
      zuvPart, nullptr, cnt, 640, b1P, Z1uvB, 4096,
      NULSTATE, nullptr, 0, nullptr);
  // Va = Vmat @ Wva^T + bva (fused sum, cnt base 448; vaPart overlays dead W1uv)
  k_g4<2, 8, true, true, EPI_SUMF32><<<dim3(4, 8, 36), 256, 0, stream>>>(
      VmatHi, VmatLo, 2048, WvaHi, WvaLo, 2048, 256, 4608,
      vaPart, nullptr, cnt, 448, bva, VaBuf, 256,
      NULSTATE, nullptr, 0, nullptr);
  // W2d pack (overwrites staging arena)
  k_permpk<<<4096, 256, 0, stream>>>(W2dHi, W2dLo, Wi2, 3072, 0, 3072, Wh2, 1024, 4096);
  // Z1emb = emb @ W1e^T -> bf16 direct
  k_g4<8, 1, false, false, EPI_BF16D><<<dim3(64, 1, 40), 256, 0, stream>>>(
      AembBF, nullptr, 1024, W1ePk, nullptr, 1024, 4096, 5120,
      nullptr, Z1embB, cnt, 0, nullptr, nullptr, 0,
      NULSTATE, nullptr, 0, nullptr);

  for (int t = 0; t < T_; t++) {
    const short* xcH = x1Hi + (size_t)(t & 1) * (128 * 2048);
    const short* xcL = x1Lo + (size_t)(t & 1) * (128 * 2048);
    short* xnH = x1Hi + (size_t)((t + 1) & 1) * (128 * 2048);
    short* xnL = x1Lo + (size_t)((t + 1) & 1) * (128 * 2048);
    // G1: gates1 GEMM + fused LSTM1 epilogue (cnt 0..63)
    k_g4<2, 8, true, true, EPI_LSTM1><<<dim3(64, 8, 1), 256, 0, stream>>>(
        xcH, xcL, 2048, W1dHi, W1dLo, 2048, 4096, 128,
        partG, nullptr, cnt, 0, nullptr, nullptr, 0,
        Z1uvB, Z1embB, c1, xcH, xcL, xnH, xnL, x2Hi, x2Lo,
        nullptr, nullptr, lengths, t, nullptr);
    // HA: ha = h1n @ Wha^T + bha (fused sum -> haB, cnt 64..67)
    k_g4<1, 8, true, true, EPI_SUMF32><<<dim3(4, 8, 1), 256, 0, stream>>>(
        x2Hi + 2048, x2Lo + 2048, 4096, WhaHi, WhaLo, 1024, 256, 128,
        haPart, nullptr, cnt, 64, bha, haB, 256,
        NULSTATE, nullptr, 0, nullptr);
    // ATTN -> av into x2[:, :2048]
    k_attn<<<128, 256, 0, stream>>>(x2Hi, x2Lo, haB, wa, ba, VaBuf, Vmat);
    // G2: gates2 GEMM + fused LSTM2 epilogue (cnt 128..191)
    k_g4<4, 8, true, true, EPI_LSTM2><<<dim3(64, 8, 1), 256, 0, stream>>>(
        x2Hi, x2Lo, 4096, W2dHi, W2dLo, 4096, 4096, 128,
        partG, nullptr, cnt, 128, b2P, nullptr, 0,
        nullptr, nullptr, c2, xcH, xcL, xnH, xnL, nullptr, nullptr,
        h2nHi, h2nLo, lengths, t, nullptr);
    // LG: logits GEMM + fused mask/bias epilogue -> d_out (cnt 256..412)
    k_g4<2, 4, true, false, EPI_LOGITS><<<dim3(157, 4, 1), 256, 0, stream>>>(
        h2nHi, h2nLo, 1024, WlPK, nullptr, 1024, 10048, 128,
        partG, nullptr, cnt, 256, bl, nullptr, 0,
        NULSTATE, lengths, t, (float*)d_out);
  }
}

// Round 7
// 4154.240 us; speedup vs baseline: 1.9725x; 1.9725x over previous
//
#include <hip/hip_runtime.h>

#define EPI_PART 0
#define EPI_BF16D 1

#define T_ 40
#define VOC_ 10000

typedef __attribute__((ext_vector_type(8))) short bf16x8;
typedef __attribute__((ext_vector_type(4))) short short4v;
typedef __attribute__((ext_vector_type(8))) short short8v;
typedef __attribute__((ext_vector_type(4))) float float4v;
typedef __attribute__((ext_vector_type(4))) float f32x4;

__device__ __forceinline__ float bf2f(short s) {
  unsigned u = ((unsigned)(unsigned short)s) << 16;
  float f; __builtin_memcpy(&f, &u, 4); return f;
}
__device__ __forceinline__ short f2bf(float f) {
  unsigned u; __builtin_memcpy(&u, &f, 4);
  u += 0x7FFFu + ((u >> 16) & 1u);
  return (short)(u >> 16);
}
__device__ __forceinline__ float sigm(float x) { return 1.f / (1.f + expf(-x)); }

// packed W layout: W[row][k] at (row>>4)*16*K + (k>>3)*128 + (row&15)*8 + (k&7)
__device__ __forceinline__ size_t pkidx(int row, int k, int K) {
  return (size_t)(row >> 4) * 16 * K + (size_t)(k >> 3) * 128 + (size_t)((row & 15) * 8 + (k & 7));
}

// ---------------- packing kernels ----------------

__global__ __launch_bounds__(256) void k_f2bf_split(const float* __restrict__ s,
    short* __restrict__ dh, short* __restrict__ dl, long n4) {
  long i = (long)blockIdx.x * 256 + threadIdx.x;
  long stride = (long)gridDim.x * 256;
  for (; i < n4; i += stride) {
    float4v f = ((const float4v*)s)[i];
    short4v oh, ol;
    #pragma unroll
    for (int j = 0; j < 4; j++) {
      short h = f2bf(f[j]); oh[j] = h; ol[j] = f2bf(f[j] - bf2f(h));
    }
    ((short4v*)dh)[i] = oh;
    ((short4v*)dl)[i] = ol;
  }
}

__global__ __launch_bounds__(256) void k_permpk(short* __restrict__ dh, short* __restrict__ dl,
    const float* __restrict__ s1, int ld1, int col0, int K1,
    const float* __restrict__ s2, int ld2, int Ktot) {
  int K4 = Ktot >> 2;
  long n4 = 4096L * K4;
  long stride = (long)gridDim.x * 256;
  for (long i = (long)blockIdx.x * 256 + threadIdx.x; i < n4; i += stride) {
    int p = (int)(i / K4);
    int c = ((int)(i % K4)) << 2;
    int orig = ((p & 3) << 10) + (p >> 2);
    const float* src = (c < K1) ? (s1 + (long)orig * ld1 + col0 + c)
                                : (s2 + (long)orig * ld2 + (c - K1));
    float4v f = *(const float4v*)src;
    short4v oh, ol;
    #pragma unroll
    for (int j = 0; j < 4; j++) {
      short h = f2bf(f[j]); oh[j] = h; ol[j] = f2bf(f[j] - bf2f(h));
    }
    size_t d = pkidx(p, c, Ktot);
    *(short4v*)&dh[d] = oh;
    if (dl) *(short4v*)&dl[d] = ol;
  }
}

__global__ __launch_bounds__(256) void k_packpk(short* __restrict__ dh, short* __restrict__ dl,
    const float* __restrict__ src, int ld, int Nr, int Nsrc, int K) {
  int K4 = K >> 2;
  long n4 = (long)Nr * K4;
  long stride = (long)gridDim.x * 256;
  for (long i = (long)blockIdx.x * 256 + threadIdx.x; i < n4; i += stride) {
    int row = (int)(i / K4);
    int c = ((int)(i % K4)) << 2;
    float4v f = {0.f, 0.f, 0.f, 0.f};
    if (row < Nsrc) f = *(const float4v*)(src + (long)row * ld + c);
    short4v oh, ol;
    #pragma unroll
    for (int j = 0; j < 4; j++) {
      short h = f2bf(f[j]); oh[j] = h; ol[j] = f2bf(f[j] - bf2f(h));
    }
    size_t d = pkidx(row, c, K);
    *(short4v*)&dh[d] = oh;
    if (dl) *(short4v*)&dl[d] = ol;
  }
}

__global__ __launch_bounds__(256) void k_perm_bias(float* __restrict__ d1, const float* __restrict__ s1,
                                                   float* __restrict__ d2, const float* __restrict__ s2) {
  int p = blockIdx.x * 256 + threadIdx.x;
  if (p < 4096) {
    int orig = ((p & 3) << 10) + (p >> 2);
    d1[p] = s1[orig];
    d2[p] = s2[orig];
  }
}

__global__ __launch_bounds__(256) void k_gather_emb(short* __restrict__ dst, const float* __restrict__ embW,
                                                    const int* __restrict__ cap) {
  int i = blockIdx.x * 256 + threadIdx.x;  // 5120*128
  if (i >= 5120 * 128) return;
  int row = i >> 7, c8 = (i & 127) << 3;
  int tok = cap[row];
  const float4v* s = (const float4v*)(embW + (long)tok * 1024 + c8);
  float4v f0 = s[0], f1 = s[1];
  short8v o;
  #pragma unroll
  for (int j = 0; j < 4; j++) { o[j] = f2bf(f0[j]); o[4 + j] = f2bf(f1[j]); }
  *(short8v*)(dst + (long)row * 1024 + c8) = o;
}

// Wha f32 -> [hb 0..127][ph 0..255][8] packed (coalesced 32B/lane in attn)
__global__ __launch_bounds__(256) void k_pack_whaf(float* __restrict__ dst, const float* __restrict__ Wha) {
  int i = blockIdx.x * 256 + threadIdx.x;  // 32768
  int hb = i >> 8, ph = i & 255;
  float4v a = *(const float4v*)(Wha + (long)ph * 1024 + hb * 8);
  float4v b4 = *(const float4v*)(Wha + (long)ph * 1024 + hb * 8 + 4);
  *(float4v*)(dst + ((long)hb * 256 + ph) * 8) = a;
  *(float4v*)(dst + ((long)hb * 256 + ph) * 8 + 4) = b4;
}

// ---------------- slab GEMM (fence-free), 64-k slabs, 32KB LDS, async-stage split ----------
// C[M=128/tile, N] = A @ Wpk^T. NT=64. Grid (Ntiles, KS, Mtiles); Kchunk = NCS*64.
// A-slab global loads issued into regs BEFORE compute (T14), LDS write after barrier.
// W frags preloaded to a 2-slot register ring. Wave w owns n-frag w; 8 m-frags.

template<int NCS, bool SA, bool SW, int EPI>
__global__ __launch_bounds__(256) void k_g5(
    const short* __restrict__ A, const short* __restrict__ Alo, int lda,
    const short* __restrict__ W, const short* __restrict__ Wlo, int K,
    int Npad, int Mtot,
    float* __restrict__ outf, short* __restrict__ outbf) {
  __shared__ short sh[SA ? 16384 : 8192];   // [plane][128 rows][64 k-shorts], XOR-swizzled
  const int tid = threadIdx.x;
  const int l = tid & 63, w = tid >> 6;
  const int rif = l & 15, kg = l >> 4;
  const int n0 = blockIdx.x * 64;
  const int k0 = blockIdx.y * NCS * 64;
  const int mbase = blockIdx.z * 128;

  f32x4 acc[8];
  #pragma unroll
  for (int m = 0; m < 8; m++) acc[m] = (f32x4){0.f, 0.f, 0.f, 0.f};

  bf16x8 wh[2][2], wl[2][2];
  const size_t wtile = (size_t)(n0 / 16 + w) * 16 * K + (size_t)l * 8;
  auto loadW = [&](int c, int slot) {
    size_t base = wtile + (size_t)((k0 + c * 64) >> 3) * 128;
    #pragma unroll
    for (int sk = 0; sk < 2; sk++) {
      wh[slot][sk] = *(const bf16x8*)(W + base + sk * 512);
      if (SW) wl[slot][sk] = *(const bf16x8*)(Wlo + base + sk * 512);
    }
  };

  short8v rA[4], rL[4];
  const int srow = tid >> 3;            // 0..31
  const int scol = (tid & 7) * 8;       // k-shorts 0..56
  auto ldA = [&](int c) {               // issue global loads into regs
    #pragma unroll
    for (int j = 0; j < 4; j++) {
      size_t g = (size_t)(mbase + j * 32 + srow) * lda + k0 + c * 64 + scol;
      rA[j] = *(const short8v*)(A + g);
      if (SA) rL[j] = *(const short8v*)(Alo + g);
    }
  };
  auto stA = [&]() {                    // regs -> LDS (swizzled)
    #pragma unroll
    for (int j = 0; j < 4; j++) {
      int row = j * 32 + srow;
      int idx = row * 64 + (scol ^ ((row & 7) << 3));
      *(short8v*)&sh[idx] = rA[j];
      if (SA) *(short8v*)&sh[8192 + idx] = rL[j];
    }
  };
  auto compute = [&](int slot) {
    #pragma unroll
    for (int sk = 0; sk < 2; sk++) {
      int colb = ((sk * 32 + kg * 8) ^ ((rif & 7) << 3));
      #pragma unroll
      for (int m = 0; m < 8; m++) {
        int idx = (m * 16 + rif) * 64 + colb;
        bf16x8 ah = *(const bf16x8*)&sh[idx];
        acc[m] = __builtin_amdgcn_mfma_f32_16x16x32_bf16(ah, wh[slot][sk], acc[m], 0, 0, 0);
        if (SA) {
          bf16x8 al = *(const bf16x8*)&sh[8192 + idx];
          acc[m] = __builtin_amdgcn_mfma_f32_16x16x32_bf16(al, wh[slot][sk], acc[m], 0, 0, 0);
        }
        if (SW) acc[m] = __builtin_amdgcn_mfma_f32_16x16x32_bf16(ah, wl[slot][sk], acc[m], 0, 0, 0);
      }
    }
  };

  ldA(0); loadW(0, 0);
  stA();
  __syncthreads();
  #pragma unroll
  for (int c = 0; c < NCS; c++) {
    if (c + 1 < NCS) { ldA(c + 1); loadW(c + 1, (c + 1) & 1); }
    compute(c & 1);
    __syncthreads();
    if (c + 1 < NCS) { stA(); __syncthreads(); }
  }

  const int colw = n0 + w * 16 + rif;
  #pragma unroll
  for (int m = 0; m < 8; m++) {
    #pragma unroll
    for (int j = 0; j < 4; j++) {
      int row = m * 16 + kg * 4 + j;
      if constexpr (EPI == EPI_PART) {
        outf[((size_t)blockIdx.y * Mtot + mbase + row) * Npad + colw] = acc[m][j];
      } else {
        outbf[(size_t)(mbase + row) * Npad + colw] = f2bf(acc[m][j]);
      }
    }
  }
}

// ---------------- partial sum (+bias) -> f32 ----------------
__global__ __launch_bounds__(256) void k_sum(const float* __restrict__ part,
    float* __restrict__ out, const float* __restrict__ bias,
    long n4, int N4, int KS, long stride4) {
  long i = (long)blockIdx.x * 256 + threadIdx.x;
  if (i >= n4) return;
  float4v a = *(const float4v*)&bias[(i % N4) * 4];
  for (int s = 0; s < KS; s++) {
    float4v p = ((const float4v*)part)[s * stride4 + i];
    #pragma unroll
    for (int j = 0; j < 4; j++) a[j] += p[j];
  }
  ((float4v*)out)[i] = a;
}

// ---------------- LSTM2 epilogue: sum 8 partials + cell + state staging ----------------
__global__ __launch_bounds__(256) void k_epi2(
    const float* __restrict__ part, const float* __restrict__ b2p,
    float* __restrict__ cstate,
    const short* __restrict__ xcur_hi, const short* __restrict__ xcur_lo,
    short* __restrict__ xnext_hi, short* __restrict__ xnext_lo,
    short* __restrict__ h2n_hi, short* __restrict__ h2n_lo,
    const int* __restrict__ lengths, int t) {
  int i = blockIdx.x * 256 + threadIdx.x;   // 131072 = 128 b x 1024 h
  int b = i >> 10, h = i & 1023;
  float4v g = *(const float4v*)&b2p[h * 4];
  #pragma unroll
  for (int s = 0; s < 8; s++) {
    float4v p = *(const float4v*)&part[((size_t)s * 128 + b) * 4096 + h * 4];
    #pragma unroll
    for (int j = 0; j < 4; j++) g[j] += p[j];
  }
  float co = cstate[b * 1024 + h];
  float cn = sigm(g[1]) * co + sigm(g[0]) * tanhf(g[2]);
  float hn = sigm(g[3]) * tanhf(cn);
  bool act = lengths[b] > t;
  cstate[b * 1024 + h] = act ? cn : co;
  short hi16 = f2bf(hn);
  short lo16 = f2bf(hn - bf2f(hi16));
  h2n_hi[b * 1024 + h] = hi16;
  h2n_lo[b * 1024 + h] = lo16;
  short oh = xcur_hi[b * 2048 + h];
  short ol = xcur_lo[b * 2048 + h];
  xnext_hi[b * 2048 + h] = act ? hi16 : oh;
  xnext_lo[b * 2048 + h] = act ? lo16 : ol;
}

// ---------------- logits epilogue: sum 4 partials + bias + mask -> d_out ----------------
__global__ __launch_bounds__(256) void k_epi_logits(const float* __restrict__ part,
    const float* __restrict__ bl, const int* __restrict__ lengths, int t,
    float* __restrict__ out) {
  int id = blockIdx.x * 256 + threadIdx.x;   // 320000 = 128 b x 2500 col4
  if (id >= 320000) return;
  int b = id / 2500, q = (id % 2500) * 4;
  bool act = lengths[b] > t;
  float4v a = {0.f, 0.f, 0.f, 0.f};
  if (act) {
    a = *(const float4v*)&bl[q];
    #pragma unroll
    for (int s = 0; s < 4; s++) {
      float4v p = *(const float4v*)&part[((size_t)s * 128 + b) * 10048 + q];
      #pragma unroll
      for (int j = 0; j < 4; j++) a[j] += p[j];
    }
  }
  *(float4v*)&out[((size_t)b * T_ + t) * VOC_ + q] = a;
}

// ---------------- fused LSTM1-epilogue + ha + attention, one block per batch ----------------
__global__ __launch_bounds__(256) void k_attn2(
    const float* __restrict__ partG,            // [8][128][4096]
    const float* __restrict__ zuv, const short* __restrict__ zemb,
    float* __restrict__ c1,
    const short* __restrict__ xcH, const short* __restrict__ xcL,
    short* __restrict__ xnH, short* __restrict__ xnL,
    short* __restrict__ x2H, short* __restrict__ x2L,
    const float* __restrict__ WhaF,             // [128][256][8] f32
    const float* __restrict__ bha, const float* __restrict__ wa,
    const float* __restrict__ ba, const float* __restrict__ Va,
    const float* __restrict__ Vmat,
    const int* __restrict__ lengths, int t) {
  const int b = blockIdx.x, tid = threadIdx.x;
  __shared__ float h1f[1024];
  __shared__ float ha_sh[256];
  __shared__ float wa_sh[256];
  __shared__ float logit_sh[40];
  __shared__ float p_sh[40];
  const bool act = lengths[b] > t;
  // LSTM1 epilogue: 4 h per thread (same fixed s-order sum as before)
  #pragma unroll
  for (int i = 0; i < 4; i++) {
    int h = i * 256 + tid;
    float4v g = {0.f, 0.f, 0.f, 0.f};
    #pragma unroll
    for (int s = 0; s < 8; s++) {
      float4v p = *(const float4v*)&partG[((size_t)s * 128 + b) * 4096 + h * 4];
      #pragma unroll
      for (int j = 0; j < 4; j++) g[j] += p[j];
    }
    float4v z = *(const float4v*)&zuv[(size_t)b * 4096 + h * 4];   // includes b1
    short4v e4 = *(const short4v*)&zemb[((size_t)b * T_ + t) * 4096 + h * 4];
    #pragma unroll
    for (int j = 0; j < 4; j++) g[j] += z[j] + bf2f(e4[j]);
    float co = c1[b * 1024 + h];
    float cn = sigm(g[1]) * co + sigm(g[0]) * tanhf(g[2]);
    float hn = sigm(g[3]) * tanhf(cn);
    c1[b * 1024 + h] = act ? cn : co;
    h1f[h] = hn;
    short hi16 = f2bf(hn);
    short lo16 = f2bf(hn - bf2f(hi16));
    x2H[b * 4096 + 2048 + h] = hi16;                 // h1n (fresh) for gates2
    x2L[b * 4096 + 2048 + h] = lo16;
    short oh = xcH[b * 2048 + 1024 + h];
    short ol = xcL[b * 2048 + 1024 + h];
    xnH[b * 2048 + 1024 + h] = act ? hi16 : oh;      // frozen h1 state
    xnL[b * 2048 + 1024 + h] = act ? lo16 : ol;
    x2H[b * 4096 + 3072 + h] = xcH[b * 2048 + h];    // copy h2 state into x2
    x2L[b * 4096 + 3072 + h] = xcL[b * 2048 + h];
  }
  wa_sh[tid] = wa[tid];
  __syncthreads();
  {  // ha[ph] = Wha[ph,:] . h1n + bha[ph]  (exact f32, coalesced packed layout)
    float a = 0.f;
    const float* wp = WhaF + tid * 8;
    #pragma unroll 4
    for (int hb = 0; hb < 128; hb++) {
      float4v w0 = *(const float4v*)(wp + (size_t)hb * 2048);
      float4v w1 = *(const float4v*)(wp + (size_t)hb * 2048 + 4);
      #pragma unroll
      for (int j = 0; j < 4; j++) a += w0[j] * h1f[hb * 8 + j] + w1[j] * h1f[hb * 8 + 4 + j];
    }
    ha_sh[tid] = a + bha[tid];
  }
  __syncthreads();
  {  // logit[r] = sum_ph tanh(Va + ha)*wa + ba
    const int r0 = tid >> 3, sl = tid & 7;
    const float ba0 = ba[0];
    for (int r = r0; r < 36; r += 32) {
      const float4v* va4 = (const float4v*)(Va + ((long)b * 36 + r) * 256 + sl * 32);
      float part = 0.f;
      #pragma unroll
      for (int q = 0; q < 8; q++) {
        float4v v4 = va4[q];
        #pragma unroll
        for (int j = 0; j < 4; j++) {
          int ph = sl * 32 + q * 4 + j;
          part += tanhf(v4[j] + ha_sh[ph]) * wa_sh[ph];
        }
      }
      part += __shfl_down(part, 4, 8);
      part += __shfl_down(part, 2, 8);
      part += __shfl_down(part, 1, 8);
      if (sl == 0) logit_sh[r] = part + ba0;
    }
  }
  __syncthreads();
  if (tid < 64) {  // softmax over R=36
    float v = (tid < 36) ? logit_sh[tid] : -3.4e38f;
    float m = v;
    #pragma unroll
    for (int off = 32; off > 0; off >>= 1) m = fmaxf(m, __shfl_xor(m, off));
    float e = (tid < 36) ? expf(v - m) : 0.f;
    float s = e;
    #pragma unroll
    for (int off = 32; off > 0; off >>= 1) s += __shfl_xor(s, off);
    if (tid < 36) p_sh[tid] = e / s;
  }
  __syncthreads();
  {  // av = sum_r p[r] * Vmat[b,r,:]  (f32 exact) -> split hi/lo into x2
    float av[8];
    #pragma unroll
    for (int j = 0; j < 8; j++) av[j] = 0.f;
    const float* vb = Vmat + (long)b * (36 * 2048) + tid * 8;
    for (int r = 0; r < 36; r++) {
      float p = p_sh[r];
      float4v v0 = *(const float4v*)(vb + (long)r * 2048);
      float4v v1 = *(const float4v*)(vb + (long)r * 2048 + 4);
      #pragma unroll
      for (int j = 0; j < 4; j++) { av[j] += p * v0[j]; av[4 + j] += p * v1[j]; }
    }
    short8v oh, ol;
    #pragma unroll
    for (int j = 0; j < 8; j++) {
      short h = f2bf(av[j]);
      oh[j] = h;
      ol[j] = f2bf(av[j] - bf2f(h));
    }
    *(short8v*)(x2H + b * 4096 + tid * 8) = oh;
    *(short8v*)(x2L + b * 4096 + tid * 8) = ol;
  }
}

// ---------------- host launcher ----------------
extern "C" void kernel_launch(void* const* d_in, const int* in_sizes, int n_in,
                              void* d_out, int out_size, void* d_ws, size_t ws_size,
                              hipStream_t stream) {
  const float* Vmat = (const float*)d_in[0];
  const float* uv   = (const float*)d_in[2];
  const int* captions = (const int*)d_in[3];
  const int* lengths  = (const int*)d_in[4];
  const float* embW = (const float*)d_in[5];
  const float* Wi1 = (const float*)d_in[6];
  const float* Wh1 = (const float*)d_in[7];
  const float* b1  = (const float*)d_in[8];
  const float* Wi2 = (const float*)d_in[9];
  const float* Wh2 = (const float*)d_in[10];
  const float* b2  = (const float*)d_in[11];
  const float* Wva = (const float*)d_in[12];
  const float* bva = (const float*)d_in[13];
  const float* Wha = (const float*)d_in[14];
  const float* bha = (const float*)d_in[15];
  const float* wa  = (const float*)d_in[16];
  const float* ba  = (const float*)d_in[17];
  const float* Wl  = (const float*)d_in[18];
  const float* bl  = (const float*)d_in[19];
  (void)in_sizes; (void)n_in; (void)out_size; (void)ws_size;

  char* ws = (char*)d_ws;
  size_t off = 0;
  auto alloc = [&](size_t bytes) { void* p = ws + off; off += (bytes + 255) & ~255UL; return p; };
  short* W1dHi = (short*)alloc(4096L * 2048 * 2);
  short* W1dLo = (short*)alloc(4096L * 2048 * 2);
  short* W2dHi = (short*)alloc(4096L * 4096 * 2);   // staging arena pre-loop
  short* W2dLo = (short*)alloc(4096L * 4096 * 2);
  short* WlPK  = (short*)alloc(10048L * 1024 * 2);
  float* WhaF  = (float*)alloc(128L * 256 * 8 * 4); // packed f32 Wha
  float* VaBuf = (float*)alloc(4608L * 256 * 4);
  float* Z1uvB = (float*)alloc(128L * 4096 * 4);
  short* Z1embB = (short*)alloc(5120L * 4096 * 2);  // hosts Vmat hi/lo split pre-loop
  float* partG = (float*)alloc(4L * 128 * 10048 * 4); // 20.6MB partials arena; W1e+Aemb pre-loop
  float* b1P = (float*)alloc(4096 * 4);
  float* b2P = (float*)alloc(4096 * 4);
  short* x1Hi = (short*)alloc(2L * 128 * 2048 * 2);
  short* x1Lo = (short*)alloc(2L * 128 * 2048 * 2);
  short* x2Hi = (short*)alloc(128L * 4096 * 2);     // [av | h1n | h2]
  short* x2Lo = (short*)alloc(128L * 4096 * 2);
  short* h2nHi = (short*)alloc(128L * 1024 * 2);
  short* h2nLo = (short*)alloc(128L * 1024 * 2);
  float* c1 = (float*)alloc(128L * 1024 * 4);
  float* c2 = (float*)alloc(128L * 1024 * 4);

  // aliased one-time regions
  short* W1uvHi = W2dHi;
  short* W1uvLo = W2dHi + 4096L * 2048;
  float* zuvPart = (float*)(W2dHi + 4096L * 4096);             // [8][128][4096] f32
  short* uvHi = W2dHi + 4096L * 4096 + 4096L * 2048 + 2097152;
  short* uvLo = uvHi + 128L * 2048;
  short* WvaHi = uvLo + 128L * 2048;
  short* WvaLo = WvaHi + 256L * 2048;
  float* vaPart = (float*)W2dHi;                               // [8][4608][256] after W1uv dead
  short* W1ePk = (short*)partG;
  short* AembBF = (short*)partG + 4096L * 1024;
  short* VmatHi = Z1embB;
  short* VmatLo = Z1embB + 4608L * 2048;

  (void)hipMemsetAsync(x1Hi, 0, 2L * 128 * 2048 * 2, stream);
  (void)hipMemsetAsync(x1Lo, 0, 2L * 128 * 2048 * 2, stream);
  (void)hipMemsetAsync(c1, 0, 128L * 1024 * 4, stream);
  (void)hipMemsetAsync(c2, 0, 128L * 1024 * 4, stream);

  // ---- packing ----
  k_packpk<<<2048, 256, 0, stream>>>(WlPK, nullptr, Wl, 1024, 10048, 10000, 1024);
  k_pack_whaf<<<128, 256, 0, stream>>>(WhaF, Wha);
  k_packpk<<<512, 256, 0, stream>>>(WvaHi, WvaLo, Wva, 2048, 256, 256, 2048);
  k_permpk<<<2048, 256, 0, stream>>>(W1dHi, W1dLo, Wi1, 4096, 0, 1024, Wh1, 1024, 2048);
  k_permpk<<<2048, 256, 0, stream>>>(W1uvHi, W1uvLo, Wi1, 4096, 1024, 2048, Wi1, 4096, 2048);
  k_permpk<<<1024, 256, 0, stream>>>(W1ePk, nullptr, Wi1, 4096, 3072, 1024, Wi1, 4096, 1024);
  k_perm_bias<<<16, 256, 0, stream>>>(b1P, b1, b2P, b2);
  k_gather_emb<<<2560, 256, 0, stream>>>(AembBF, embW, captions);
  k_f2bf_split<<<2048, 256, 0, stream>>>(Vmat, VmatHi, VmatLo, 128L * 36 * 2048 / 4);
  k_f2bf_split<<<64, 256, 0, stream>>>(uv, uvHi, uvLo, 128L * 2048 / 4);

  // Z1uv = uv @ W1uv^T + b1 (perm): partials + sum
  k_g5<4, true, true, EPI_PART><<<dim3(64, 8, 1), 256, 0, stream>>>(
      uvHi, uvLo, 2048, W1uvHi, W1uvLo, 2048, 4096, 128, zuvPart, nullptr);
  k_sum<<<512, 256, 0, stream>>>(zuvPart, Z1uvB, b1P, 131072, 1024, 8, 131072);
  // Va = Vmat @ Wva^T + bva (vaPart overlays dead W1uv+zuv region)
  k_g5<4, true, true, EPI_PART><<<dim3(4, 8, 36), 256, 0, stream>>>(
      VmatHi, VmatLo, 2048, WvaHi, WvaLo, 2048, 256, 4608, vaPart, nullptr);
  k_sum<<<1152, 256, 0, stream>>>(vaPart, VaBuf, bva, 294912, 64, 8, 294912);
  // W2d pack (overwrites staging arena)
  k_permpk<<<4096, 256, 0, stream>>>(W2dHi, W2dLo, Wi2, 3072, 0, 3072, Wh2, 1024, 4096);
  // Z1emb = emb @ W1e^T -> bf16 direct (frees Vmat split region)
  k_g5<16, false, false, EPI_BF16D><<<dim3(64, 1, 40), 256, 0, stream>>>(
      AembBF, nullptr, 1024, W1ePk, nullptr, 1024, 4096, 5120, nullptr, Z1embB);

  for (int t = 0; t < T_; t++) {
    const short* xcH = x1Hi + (size_t)(t & 1) * (128 * 2048);
    const short* xcL = x1Lo + (size_t)(t & 1) * (128 * 2048);
    short* xnH = x1Hi + (size_t)((t + 1) & 1) * (128 * 2048);
    short* xnL = x1Lo + (size_t)((t + 1) & 1) * (128 * 2048);
    // G1: gates1 partials [8][128][4096]
    k_g5<4, true, true, EPI_PART><<<dim3(64, 8, 1), 256, 0, stream>>>(
        xcH, xcL, 2048, W1dHi, W1dLo, 2048, 4096, 128, partG, nullptr);
    // ATTN2: LSTM1 epilogue + ha + attention -> x2, c1, xnext(h1)
    k_attn2<<<128, 256, 0, stream>>>(partG, Z1uvB, Z1embB, c1,
        xcH, xcL, xnH, xnL, x2Hi, x2Lo, WhaF, bha, wa, ba, VaBuf, Vmat, lengths, t);
    // G2: gates2 partials [8][128][4096]
    k_g5<8, true, true, EPI_PART><<<dim3(64, 8, 1), 256, 0, stream>>>(
        x2Hi, x2Lo, 4096, W2dHi, W2dLo, 4096, 4096, 128, partG, nullptr);
    // EPI2 -> c2, h2n, xnext(h2)
    k_epi2<<<512, 256, 0, stream>>>(partG, b2P, c2,
        xcH, xcL, xnH, xnL, h2nHi, h2nLo, lengths, t);
    // LG: logits partials [4][128][10048]
    k_g5<4, true, false, EPI_PART><<<dim3(157, 4, 1), 256, 0, stream>>>(
        h2nHi, h2nLo, 1024, WlPK, nullptr, 1024, 10048, 128, partG, nullptr);
    // EPILG -> d_out
    k_epi_logits<<<1250, 256, 0, stream>>>(partG, bl, lengths, t, (float*)d_out);
  }
}

// Round 8
// 3689.412 us; speedup vs baseline: 2.2210x; 1.1260x over previous
//
#include <hip/hip_runtime.h>

#define EPI_PART 0
#define EPI_BF16D 1

#define T_ 40
#define VOC_ 10000

typedef __attribute__((ext_vector_type(8))) short bf16x8;
typedef __attribute__((ext_vector_type(4))) short short4v;
typedef __attribute__((ext_vector_type(8))) short short8v;
typedef __attribute__((ext_vector_type(4))) float float4v;
typedef __attribute__((ext_vector_type(4))) float f32x4;

__device__ __forceinline__ float bf2f(short s) {
  unsigned u = ((unsigned)(unsigned short)s) << 16;
  float f; __builtin_memcpy(&f, &u, 4); return f;
}
__device__ __forceinline__ short f2bf(float f) {
  unsigned u; __builtin_memcpy(&u, &f, 4);
  u += 0x7FFFu + ((u >> 16) & 1u);
  return (short)(u >> 16);
}
__device__ __forceinline__ float sigm(float x) { return 1.f / (1.f + expf(-x)); }

// packed W layout: W[row][k] at (row>>4)*16*K + (k>>3)*128 + (row&15)*8 + (k&7)
__device__ __forceinline__ size_t pkidx(int row, int k, int K) {
  return (size_t)(row >> 4) * 16 * K + (size_t)(k >> 3) * 128 + (size_t)((row & 15) * 8 + (k & 7));
}

// ---------------- packing kernels ----------------

__global__ __launch_bounds__(256) void k_f2bf_split(const float* __restrict__ s,
    short* __restrict__ dh, short* __restrict__ dl, long n4) {
  long i = (long)blockIdx.x * 256 + threadIdx.x;
  long stride = (long)gridDim.x * 256;
  for (; i < n4; i += stride) {
    float4v f = ((const float4v*)s)[i];
    short4v oh, ol;
    #pragma unroll
    for (int j = 0; j < 4; j++) {
      short h = f2bf(f[j]); oh[j] = h; ol[j] = f2bf(f[j] - bf2f(h));
    }
    ((short4v*)dh)[i] = oh;
    ((short4v*)dl)[i] = ol;
  }
}

__global__ __launch_bounds__(256) void k_permpk(short* __restrict__ dh, short* __restrict__ dl,
    const float* __restrict__ s1, int ld1, int col0, int K1,
    const float* __restrict__ s2, int ld2, int Ktot) {
  int K4 = Ktot >> 2;
  long n4 = 4096L * K4;
  long stride = (long)gridDim.x * 256;
  for (long i = (long)blockIdx.x * 256 + threadIdx.x; i < n4; i += stride) {
    int p = (int)(i / K4);
    int c = ((int)(i % K4)) << 2;
    int orig = ((p & 3) << 10) + (p >> 2);
    const float* src = (c < K1) ? (s1 + (long)orig * ld1 + col0 + c)
                                : (s2 + (long)orig * ld2 + (c - K1));
    float4v f = *(const float4v*)src;
    short4v oh, ol;
    #pragma unroll
    for (int j = 0; j < 4; j++) {
      short h = f2bf(f[j]); oh[j] = h; ol[j] = f2bf(f[j] - bf2f(h));
    }
    size_t d = pkidx(p, c, Ktot);
    *(short4v*)&dh[d] = oh;
    if (dl) *(short4v*)&dl[d] = ol;
  }
}

__global__ __launch_bounds__(256) void k_packpk(short* __restrict__ dh, short* __restrict__ dl,
    const float* __restrict__ src, int ld, int Nr, int Nsrc, int K) {
  int K4 = K >> 2;
  long n4 = (long)Nr * K4;
  long stride = (long)gridDim.x * 256;
  for (long i = (long)blockIdx.x * 256 + threadIdx.x; i < n4; i += stride) {
    int row = (int)(i / K4);
    int c = ((int)(i % K4)) << 2;
    float4v f = {0.f, 0.f, 0.f, 0.f};
    if (row < Nsrc) f = *(const float4v*)(src + (long)row * ld + c);
    short4v oh, ol;
    #pragma unroll
    for (int j = 0; j < 4; j++) {
      short h = f2bf(f[j]); oh[j] = h; ol[j] = f2bf(f[j] - bf2f(h));
    }
    size_t d = pkidx(row, c, K);
    *(short4v*)&dh[d] = oh;
    if (dl) *(short4v*)&dl[d] = ol;
  }
}

__global__ __launch_bounds__(256) void k_perm_bias(float* __restrict__ d1, const float* __restrict__ s1,
                                                   float* __restrict__ d2, const float* __restrict__ s2) {
  int p = blockIdx.x * 256 + threadIdx.x;
  if (p < 4096) {
    int orig = ((p & 3) << 10) + (p >> 2);
    d1[p] = s1[orig];
    d2[p] = s2[orig];
  }
}

__global__ __launch_bounds__(256) void k_gather_emb(short* __restrict__ dst, const float* __restrict__ embW,
                                                    const int* __restrict__ cap) {
  int i = blockIdx.x * 256 + threadIdx.x;  // 5120*128
  if (i >= 5120 * 128) return;
  int row = i >> 7, c8 = (i & 127) << 3;
  int tok = cap[row];
  const float4v* s = (const float4v*)(embW + (long)tok * 1024 + c8);
  float4v f0 = s[0], f1 = s[1];
  short8v o;
  #pragma unroll
  for (int j = 0; j < 4; j++) { o[j] = f2bf(f0[j]); o[4 + j] = f2bf(f1[j]); }
  *(short8v*)(dst + (long)row * 1024 + c8) = o;
}

// Wha f32 -> [hb 0..127][ph 0..255][8] packed
__global__ __launch_bounds__(256) void k_pack_whaf(float* __restrict__ dst, const float* __restrict__ Wha) {
  int i = blockIdx.x * 256 + threadIdx.x;  // 32768
  int hb = i >> 8, ph = i & 255;
  float4v a = *(const float4v*)(Wha + (long)ph * 1024 + hb * 8);
  float4v b4 = *(const float4v*)(Wha + (long)ph * 1024 + hb * 8 + 4);
  *(float4v*)(dst + ((long)hb * 256 + ph) * 8) = a;
  *(float4v*)(dst + ((long)hb * 256 + ph) * 8 + 4) = b4;
}

// ---------------- GEMM body: 4 waves x 2 n-frags (128-col tile), 64-k slabs ----------------
// A[128 rows, K] hi/lo staged to XOR-swizzled LDS (reg-split async stage);
// W frags 2-slot register ring. acc[8 m][2 nf]. One k-slab = 64.

template<int NCS, bool SA, bool SW, int EPI>
__device__ __forceinline__ void gemm_body(short* sh, int bx, int ks, int mb,
    const short* __restrict__ A, const short* __restrict__ Alo, int lda,
    const short* __restrict__ W, const short* __restrict__ Wlo, int K,
    int Npad, int Mtot, float* __restrict__ part, short* __restrict__ outbf) {
  const int tid = threadIdx.x;
  const int l = tid & 63, w = tid >> 6;
  const int rif = l & 15, kg = l >> 4;
  const int n0 = bx * 128;
  const int k0 = ks * NCS * 64;
  const int mbase = mb * 128;

  f32x4 acc[8][2];
  #pragma unroll
  for (int m = 0; m < 8; m++) {
    acc[m][0] = (f32x4){0.f, 0.f, 0.f, 0.f};
    acc[m][1] = (f32x4){0.f, 0.f, 0.f, 0.f};
  }

  bf16x8 wh[2][2][2], wl[2][2][2];    // [slot][sk][nf]
  size_t wt0 = (size_t)(n0 / 16 + w * 2) * 16 * K + (size_t)l * 8;
  size_t wt1 = wt0 + (size_t)16 * K;
  auto loadW = [&](int c, int slot) {
    size_t base = (size_t)((k0 + c * 64) >> 3) * 128;
    #pragma unroll
    for (int sk = 0; sk < 2; sk++) {
      wh[slot][sk][0] = *(const bf16x8*)(W + wt0 + base + sk * 512);
      wh[slot][sk][1] = *(const bf16x8*)(W + wt1 + base + sk * 512);
      if (SW) {
        wl[slot][sk][0] = *(const bf16x8*)(Wlo + wt0 + base + sk * 512);
        wl[slot][sk][1] = *(const bf16x8*)(Wlo + wt1 + base + sk * 512);
      }
    }
  };

  short8v rA[4], rL[4];
  const int srow = tid >> 3;            // 0..31
  const int scol = (tid & 7) * 8;       // 0..56
  auto ldA = [&](int c) {
    #pragma unroll
    for (int j = 0; j < 4; j++) {
      size_t g = (size_t)(mbase + j * 32 + srow) * lda + k0 + c * 64 + scol;
      rA[j] = *(const short8v*)(A + g);
      if (SA) rL[j] = *(const short8v*)(Alo + g);
    }
  };
  auto stA = [&]() {
    #pragma unroll
    for (int j = 0; j < 4; j++) {
      int row = j * 32 + srow;
      int idx = row * 64 + (scol ^ ((row & 7) << 3));
      *(short8v*)&sh[idx] = rA[j];
      if (SA) *(short8v*)&sh[8192 + idx] = rL[j];
    }
  };
  auto compute = [&](int slot) {
    #pragma unroll
    for (int sk = 0; sk < 2; sk++) {
      int colb = ((sk * 32 + kg * 8) ^ ((rif & 7) << 3));
      #pragma unroll
      for (int m = 0; m < 8; m++) {
        int idx = (m * 16 + rif) * 64 + colb;
        bf16x8 ah = *(const bf16x8*)&sh[idx];
        bf16x8 al;
        if (SA) al = *(const bf16x8*)&sh[8192 + idx];
        #pragma unroll
        for (int nf = 0; nf < 2; nf++) {
          acc[m][nf] = __builtin_amdgcn_mfma_f32_16x16x32_bf16(ah, wh[slot][0][nf] * 0 + wh[slot][sk][nf], acc[m][nf], 0, 0, 0);
          if (SA) acc[m][nf] = __builtin_amdgcn_mfma_f32_16x16x32_bf16(al, wh[slot][sk][nf], acc[m][nf], 0, 0, 0);
          if (SW) acc[m][nf] = __builtin_amdgcn_mfma_f32_16x16x32_bf16(ah, wl[slot][sk][nf], acc[m][nf], 0, 0, 0);
        }
      }
    }
  };

  ldA(0); loadW(0, 0);
  stA();
  __syncthreads();
  #pragma unroll
  for (int c = 0; c < NCS; c++) {
    if (c + 1 < NCS) { ldA(c + 1); loadW(c + 1, (c + 1) & 1); }
    compute(c & 1);
    __syncthreads();
    if (c + 1 < NCS) { stA(); __syncthreads(); }
  }

  #pragma unroll
  for (int nf = 0; nf < 2; nf++) {
    int colw = n0 + (w * 2 + nf) * 16 + rif;
    #pragma unroll
    for (int m = 0; m < 8; m++) {
      #pragma unroll
      for (int j = 0; j < 4; j++) {
        int row = m * 16 + kg * 4 + j;
        if constexpr (EPI == EPI_PART) {
          part[((size_t)ks * Mtot + mbase + row) * Npad + colw] = acc[m][nf][j];
        } else {
          outbf[(size_t)(mbase + row) * Npad + colw] = f2bf(acc[m][nf][j]);
        }
      }
    }
  }
}

// standalone GEMM kernel (pre-loop uses)
template<int NCS, bool SA, bool SW, int EPI>
__global__ __launch_bounds__(256) void k_g6(
    const short* __restrict__ A, const short* __restrict__ Alo, int lda,
    const short* __restrict__ W, const short* __restrict__ Wlo, int K,
    int Npad, int Mtot, float* __restrict__ part, short* __restrict__ outbf) {
  __shared__ short sh[SA ? 16384 : 8192];
  gemm_body<NCS, SA, SW, EPI>(sh, blockIdx.x, blockIdx.y, blockIdx.z,
      A, Alo, lda, W, Wlo, K, Npad, Mtot, part, outbf);
}

// ---------------- partial sum (+bias) -> f32 ----------------
__global__ __launch_bounds__(256) void k_sum(const float* __restrict__ part,
    float* __restrict__ out, const float* __restrict__ bias,
    long n4, int N4, int KS, long stride4) {
  long i = (long)blockIdx.x * 256 + threadIdx.x;
  if (i >= n4) return;
  float4v a = *(const float4v*)&bias[(i % N4) * 4];
  for (int s = 0; s < KS; s++) {
    float4v p = ((const float4v*)part)[s * stride4 + i];
    #pragma unroll
    for (int j = 0; j < 4; j++) a[j] += p[j];
  }
  ((float4v*)out)[i] = a;
}

// ---------------- LSTM2 epilogue ----------------
__global__ __launch_bounds__(256) void k_epi2(
    const float* __restrict__ part, const float* __restrict__ b2p,
    float* __restrict__ cstate,
    const short* __restrict__ xcur_hi, const short* __restrict__ xcur_lo,
    short* __restrict__ xnext_hi, short* __restrict__ xnext_lo,
    short* __restrict__ h2n_hi, short* __restrict__ h2n_lo,
    const int* __restrict__ lengths, int t) {
  int i = blockIdx.x * 256 + threadIdx.x;   // 131072 = 128 b x 1024 h
  int b = i >> 10, h = i & 1023;
  float4v g = *(const float4v*)&b2p[h * 4];
  #pragma unroll
  for (int s = 0; s < 8; s++) {
    float4v p = *(const float4v*)&part[((size_t)s * 128 + b) * 4096 + h * 4];
    #pragma unroll
    for (int j = 0; j < 4; j++) g[j] += p[j];
  }
  float co = cstate[b * 1024 + h];
  float cn = sigm(g[1]) * co + sigm(g[0]) * tanhf(g[2]);
  float hn = sigm(g[3]) * tanhf(cn);
  bool act = lengths[b] > t;
  cstate[b * 1024 + h] = act ? cn : co;
  short hi16 = f2bf(hn);
  short lo16 = f2bf(hn - bf2f(hi16));
  h2n_hi[b * 1024 + h] = hi16;
  h2n_lo[b * 1024 + h] = lo16;
  short oh = xcur_hi[b * 2048 + h];
  short ol = xcur_lo[b * 2048 + h];
  xnext_hi[b * 2048 + h] = act ? hi16 : oh;
  xnext_lo[b * 2048 + h] = act ? lo16 : ol;
}

// ---------------- dual A: [G1 GEMM (t)] || [logits GEMM (t-1)] ----------------
__global__ __launch_bounds__(256) void k_dualA(
    const short* __restrict__ xcH, const short* __restrict__ xcL,
    const short* __restrict__ W1dHi, const short* __restrict__ W1dLo,
    float* __restrict__ partA,
    const short* __restrict__ h2nHi, const short* __restrict__ h2nLo,
    const short* __restrict__ WlPK, float* __restrict__ partLG, int t) {
  __shared__ short sh[16384];
  int bx = blockIdx.x;
  if (bx < 256) {
    if (t >= T_) return;
    gemm_body<4, true, true, EPI_PART>(sh, bx & 31, bx >> 5, 0,
        xcH, xcL, 2048, W1dHi, W1dLo, 2048, 4096, 128, partA, nullptr);
  } else {
    if (t == 0) return;
    int f = bx - 256;                      // 0..157
    gemm_body<8, true, false, EPI_PART>(sh, f % 79, f / 79, 0,
        h2nHi, h2nLo, 1024, WlPK, nullptr, 1024, 10112, 128, partLG, nullptr);
  }
}

// ---------------- dual B: [LSTM1-epi + ha + attention (t)] || [logits epilogue (t-1)] -------
__global__ __launch_bounds__(256) void k_dualB(
    const float* __restrict__ partA,
    const float* __restrict__ zuv, const short* __restrict__ zemb,
    float* __restrict__ c1,
    const short* __restrict__ xcH, const short* __restrict__ xcL,
    short* __restrict__ xnH, short* __restrict__ xnL,
    short* __restrict__ x2H, short* __restrict__ x2L,
    const float* __restrict__ WhaF, const float* __restrict__ bha,
    const float* __restrict__ wa, const float* __restrict__ ba,
    const float* __restrict__ Va, const float* __restrict__ Vmat,
    const int* __restrict__ lengths,
    const float* __restrict__ partLG, const float* __restrict__ bl,
    float* __restrict__ out, int t) {
  __shared__ float h1f[1024];
  __shared__ float ha_sh[256];
  __shared__ float wa_sh[256];
  __shared__ float logit_sh[40];
  __shared__ float p_sh[40];
  const int tid = threadIdx.x;
  if (blockIdx.x >= 128) {
    // logits epilogue for step t-1: sum 2 partials + bias + mask -> d_out
    if (t == 0) return;
    int id = (blockIdx.x - 128) * 256 + tid;   // 320000 = 128 b x 2500 col4
    if (id >= 320000) return;
    int b = id / 2500, q = (id % 2500) * 4;
    bool act = lengths[b] > (t - 1);
    float4v a = {0.f, 0.f, 0.f, 0.f};
    if (act) {
      a = *(const float4v*)&bl[q];
      #pragma unroll
      for (int s = 0; s < 2; s++) {
        float4v p = *(const float4v*)&partLG[((size_t)s * 128 + b) * 10112 + q];
        #pragma unroll
        for (int j = 0; j < 4; j++) a[j] += p[j];
      }
    }
    *(float4v*)&out[((size_t)b * T_ + (t - 1)) * VOC_ + q] = a;
    return;
  }
  if (t >= T_) return;
  const int b = blockIdx.x;
  const bool act = lengths[b] > t;
  // LSTM1 epilogue (fixed s-order sum)
  #pragma unroll
  for (int i = 0; i < 4; i++) {
    int h = i * 256 + tid;
    float4v g = {0.f, 0.f, 0.f, 0.f};
    #pragma unroll
    for (int s = 0; s < 8; s++) {
      float4v p = *(const float4v*)&partA[((size_t)s * 128 + b) * 4096 + h * 4];
      #pragma unroll
      for (int j = 0; j < 4; j++) g[j] += p[j];
    }
    float4v z = *(const float4v*)&zuv[(size_t)b * 4096 + h * 4];   // includes b1
    short4v e4 = *(const short4v*)&zemb[((size_t)b * T_ + t) * 4096 + h * 4];
    #pragma unroll
    for (int j = 0; j < 4; j++) g[j] += z[j] + bf2f(e4[j]);
    float co = c1[b * 1024 + h];
    float cn = sigm(g[1]) * co + sigm(g[0]) * tanhf(g[2]);
    float hn = sigm(g[3]) * tanhf(cn);
    c1[b * 1024 + h] = act ? cn : co;
    h1f[h] = hn;
    short hi16 = f2bf(hn);
    short lo16 = f2bf(hn - bf2f(hi16));
    x2H[b * 4096 + 2048 + h] = hi16;
    x2L[b * 4096 + 2048 + h] = lo16;
    short oh = xcH[b * 2048 + 1024 + h];
    short ol = xcL[b * 2048 + 1024 + h];
    xnH[b * 2048 + 1024 + h] = act ? hi16 : oh;
    xnL[b * 2048 + 1024 + h] = act ? lo16 : ol;
    x2H[b * 4096 + 3072 + h] = xcH[b * 2048 + h];
    x2L[b * 4096 + 3072 + h] = xcL[b * 2048 + h];
  }
  wa_sh[tid] = wa[tid];
  __syncthreads();
  {  // ha[ph] = Wha[ph,:] . h1n + bha[ph]
    float a = 0.f;
    const float* wp = WhaF + tid * 8;
    #pragma unroll 4
    for (int hb = 0; hb < 128; hb++) {
      float4v w0 = *(const float4v*)(wp + (size_t)hb * 2048);
      float4v w1 = *(const float4v*)(wp + (size_t)hb * 2048 + 4);
      #pragma unroll
      for (int j = 0; j < 4; j++) a += w0[j] * h1f[hb * 8 + j] + w1[j] * h1f[hb * 8 + 4 + j];
    }
    ha_sh[tid] = a + bha[tid];
  }
  __syncthreads();
  {  // logit[r]
    const int r0 = tid >> 3, sl = tid & 7;
    const float ba0 = ba[0];
    for (int r = r0; r < 36; r += 32) {
      const float4v* va4 = (const float4v*)(Va + ((long)b * 36 + r) * 256 + sl * 32);
      float part = 0.f;
      #pragma unroll
      for (int q = 0; q < 8; q++) {
        float4v v4 = va4[q];
        #pragma unroll
        for (int j = 0; j < 4; j++) {
          int ph = sl * 32 + q * 4 + j;
          part += tanhf(v4[j] + ha_sh[ph]) * wa_sh[ph];
        }
      }
      part += __shfl_down(part, 4, 8);
      part += __shfl_down(part, 2, 8);
      part += __shfl_down(part, 1, 8);
      if (sl == 0) logit_sh[r] = part + ba0;
    }
  }
  __syncthreads();
  if (tid < 64) {  // softmax over R=36
    float v = (tid < 36) ? logit_sh[tid] : -3.4e38f;
    float m = v;
    #pragma unroll
    for (int off = 32; off > 0; off >>= 1) m = fmaxf(m, __shfl_xor(m, off));
    float e = (tid < 36) ? expf(v - m) : 0.f;
    float s = e;
    #pragma unroll
    for (int off = 32; off > 0; off >>= 1) s += __shfl_xor(s, off);
    if (tid < 36) p_sh[tid] = e / s;
  }
  __syncthreads();
  {  // av (f32 exact) -> split hi/lo into x2
    float av[8];
    #pragma unroll
    for (int j = 0; j < 8; j++) av[j] = 0.f;
    const float* vb = Vmat + (long)b * (36 * 2048) + tid * 8;
    for (int r = 0; r < 36; r++) {
      float p = p_sh[r];
      float4v v0 = *(const float4v*)(vb + (long)r * 2048);
      float4v v1 = *(const float4v*)(vb + (long)r * 2048 + 4);
      #pragma unroll
      for (int j = 0; j < 4; j++) { av[j] += p * v0[j]; av[4 + j] += p * v1[j]; }
    }
    short8v oh, ol;
    #pragma unroll
    for (int j = 0; j < 8; j++) {
      short h = f2bf(av[j]);
      oh[j] = h;
      ol[j] = f2bf(av[j] - bf2f(h));
    }
    *(short8v*)(x2H + b * 4096 + tid * 8) = oh;
    *(short8v*)(x2L + b * 4096 + tid * 8) = ol;
  }
}

// ---------------- host launcher ----------------
extern "C" void kernel_launch(void* const* d_in, const int* in_sizes, int n_in,
                              void* d_out, int out_size, void* d_ws, size_t ws_size,
                              hipStream_t stream) {
  const float* Vmat = (const float*)d_in[0];
  const float* uv   = (const float*)d_in[2];
  const int* captions = (const int*)d_in[3];
  const int* lengths  = (const int*)d_in[4];
  const float* embW = (const float*)d_in[5];
  const float* Wi1 = (const float*)d_in[6];
  const float* Wh1 = (const float*)d_in[7];
  const float* b1  = (const float*)d_in[8];
  const float* Wi2 = (const float*)d_in[9];
  const float* Wh2 = (const float*)d_in[10];
  const float* b2  = (const float*)d_in[11];
  const float* Wva = (const float*)d_in[12];
  const float* bva = (const float*)d_in[13];
  const float* Wha = (const float*)d_in[14];
  const float* bha = (const float*)d_in[15];
  const float* wa  = (const float*)d_in[16];
  const float* ba  = (const float*)d_in[17];
  const float* Wl  = (const float*)d_in[18];
  const float* bl  = (const float*)d_in[19];
  (void)in_sizes; (void)n_in; (void)out_size; (void)ws_size;

  char* ws = (char*)d_ws;
  size_t off = 0;
  auto alloc = [&](size_t bytes) { void* p = ws + off; off += (bytes + 255) & ~255UL; return p; };
  short* W1dHi = (short*)alloc(4096L * 2048 * 2);
  short* W1dLo = (short*)alloc(4096L * 2048 * 2);
  short* W2dHi = (short*)alloc(4096L * 4096 * 2);   // staging arena pre-loop
  short* W2dLo = (short*)alloc(4096L * 4096 * 2);
  short* WlPK  = (short*)alloc(10112L * 1024 * 2);  // packed, zero-padded rows 10000..10111
  float* WhaF  = (float*)alloc(128L * 256 * 8 * 4);
  float* VaBuf = (float*)alloc(4608L * 256 * 4);
  float* Z1uvB = (float*)alloc(128L * 4096 * 4);
  short* Z1embB = (short*)alloc(5120L * 4096 * 2);  // hosts Vmat hi/lo split pre-loop
  float* partA = (float*)alloc(8L * 128 * 4096 * 4);   // 16.8MB (G1/G2)
  float* partLG = (float*)alloc(2L * 128 * 10112 * 4); // 10.4MB (logits, KS=2)
  float* b1P = (float*)alloc(4096 * 4);
  float* b2P = (float*)alloc(4096 * 4);
  short* x1Hi = (short*)alloc(2L * 128 * 2048 * 2);
  short* x1Lo = (short*)alloc(2L * 128 * 2048 * 2);
  short* x2Hi = (short*)alloc(128L * 4096 * 2);     // [av | h1n | h2]
  short* x2Lo = (short*)alloc(128L * 4096 * 2);
  short* h2nHi = (short*)alloc(128L * 1024 * 2);
  short* h2nLo = (short*)alloc(128L * 1024 * 2);
  float* c1 = (float*)alloc(128L * 1024 * 4);
  float* c2 = (float*)alloc(128L * 1024 * 4);

  // aliased one-time regions
  short* W1uvHi = W2dHi;
  short* W1uvLo = W2dHi + 4096L * 2048;
  float* zuvPart = (float*)(W2dHi + 4096L * 4096);             // [8][128][4096] f32
  short* uvHi = W2dHi + 4096L * 4096 + 4096L * 2048 + 2097152;
  short* uvLo = uvHi + 128L * 2048;
  short* WvaHi = uvLo + 128L * 2048;
  short* WvaLo = WvaHi + 256L * 2048;
  float* vaPart = (float*)W2dHi;                               // [8][4608][256] after W1uv dead
  short* W1ePk = (short*)partA;                                // 8.4MB, dead before loop
  short* AembBF = (short*)partA + 4096L * 1024;                // 10.5MB (spans into partLG), dead before loop
  short* VmatHi = Z1embB;
  short* VmatLo = Z1embB + 4608L * 2048;

  (void)hipMemsetAsync(x1Hi, 0, 2L * 128 * 2048 * 2, stream);
  (void)hipMemsetAsync(x1Lo, 0, 2L * 128 * 2048 * 2, stream);
  (void)hipMemsetAsync(c1, 0, 128L * 1024 * 4, stream);
  (void)hipMemsetAsync(c2, 0, 128L * 1024 * 4, stream);

  // ---- packing ----
  k_packpk<<<2048, 256, 0, stream>>>(WlPK, nullptr, Wl, 1024, 10112, 10000, 1024);
  k_pack_whaf<<<128, 256, 0, stream>>>(WhaF, Wha);
  k_packpk<<<512, 256, 0, stream>>>(WvaHi, WvaLo, Wva, 2048, 256, 256, 2048);
  k_permpk<<<2048, 256, 0, stream>>>(W1dHi, W1dLo, Wi1, 4096, 0, 1024, Wh1, 1024, 2048);
  k_permpk<<<2048, 256, 0, stream>>>(W1uvHi, W1uvLo, Wi1, 4096, 1024, 2048, Wi1, 4096, 2048);
  k_permpk<<<1024, 256, 0, stream>>>(W1ePk, nullptr, Wi1, 4096, 3072, 1024, Wi1, 4096, 1024);
  k_perm_bias<<<16, 256, 0, stream>>>(b1P, b1, b2P, b2);
  k_gather_emb<<<2560, 256, 0, stream>>>(AembBF, embW, captions);
  k_f2bf_split<<<2048, 256, 0, stream>>>(Vmat, VmatHi, VmatLo, 128L * 36 * 2048 / 4);
  k_f2bf_split<<<64, 256, 0, stream>>>(uv, uvHi, uvLo, 128L * 2048 / 4);

  // Z1uv = uv @ W1uv^T + b1 (perm): partials + sum   (partials into zuvPart)
  k_g6<4, true, true, EPI_PART><<<dim3(32, 8, 1), 256, 0, stream>>>(
      uvHi, uvLo, 2048, W1uvHi, W1uvLo, 2048, 4096, 128, zuvPart, nullptr);
  k_sum<<<512, 256, 0, stream>>>(zuvPart, Z1uvB, b1P, 131072, 1024, 8, 131072);
  // Va = Vmat @ Wva^T + bva
  k_g6<4, true, true, EPI_PART><<<dim3(2, 8, 36), 256, 0, stream>>>(
      VmatHi, VmatLo, 2048, WvaHi, WvaLo, 2048, 256, 4608, vaPart, nullptr);
  k_sum<<<1152, 256, 0, stream>>>(vaPart, VaBuf, bva, 294912, 64, 8, 294912);
  // W2d pack (overwrites staging arena)
  k_permpk<<<4096, 256, 0, stream>>>(W2dHi, W2dLo, Wi2, 3072, 0, 3072, Wh2, 1024, 4096);
  // Z1emb = emb @ W1e^T -> bf16 direct (frees Vmat split region; W1ePk/Aemb die here)
  k_g6<16, false, false, EPI_BF16D><<<dim3(32, 1, 40), 256, 0, stream>>>(
      AembBF, nullptr, 1024, W1ePk, nullptr, 1024, 4096, 5120, nullptr, Z1embB);

  for (int t = 0; t <= T_; t++) {
    const short* xcH = x1Hi + (size_t)(t & 1) * (128 * 2048);
    const short* xcL = x1Lo + (size_t)(t & 1) * (128 * 2048);
    short* xnH = x1Hi + (size_t)((t + 1) & 1) * (128 * 2048);
    short* xnL = x1Lo + (size_t)((t + 1) & 1) * (128 * 2048);
    // D1: [G1(t) 256 blocks] || [logits-GEMM(t-1) 158 blocks]
    k_dualA<<<414, 256, 0, stream>>>(xcH, xcL, W1dHi, W1dLo, partA,
        h2nHi, h2nLo, WlPK, partLG, t);
    // D2: [attn2(t) 128 blocks] || [logits-epilogue(t-1) 1250 blocks]
    k_dualB<<<1378, 256, 0, stream>>>(partA, Z1uvB, Z1embB, c1,
        xcH, xcL, xnH, xnL, x2Hi, x2Lo, WhaF, bha, wa, ba, VaBuf, Vmat,
        lengths, partLG, bl, (float*)d_out, t);
    if (t < T_) {
      // D3: G2 partials [8][128][4096]
      k_g6<8, true, true, EPI_PART><<<dim3(32, 8, 1), 256, 0, stream>>>(
          x2Hi, x2Lo, 4096, W2dHi, W2dLo, 4096, 4096, 128, partA, nullptr);
      // D4: LSTM2 epilogue
      k_epi2<<<512, 256, 0, stream>>>(partA, b2P, c2,
          xcH, xcL, xnH, xnL, h2nHi, h2nLo, lengths, t);
    }
  }
}